// Round 1
// baseline (32.391 us; speedup 1.0000x reference)
//
#include <hip/hip_runtime.h>
#include <hip/hip_bf16.h>

typedef __attribute__((ext_vector_type(8))) short short8_t;
typedef __attribute__((ext_vector_type(4))) short short4_t;
typedef __attribute__((ext_vector_type(4))) float f32x4;

#define S_DIM   1024
#define D_DIM   64
#define BM      128
#define KC      64
#define NCHUNK  (S_DIM / KC)   // 16
#define BSTRIDE 72             // u16 per row of BmT chunk (pad for bank spread)
#define THREADS 512

__device__ __forceinline__ ushort f2bf(float f) {
    __hip_bfloat16 h = __float2bfloat16(f);   // RTNE
    return __builtin_bit_cast(ushort, h);
}

__global__ __launch_bounds__(THREADS, 1)
void gemm_sm_kernel(const float* __restrict__ x1,
                    const float* __restrict__ x2,
                    float* __restrict__ out) {
    // A chunk: [128 rows][64 k] bf16, XOR-swizzled (byte ^= (row&7)<<4) -> 16 KB
    __shared__ ushort lds_a[BM * KC];
    // BmT chunk: [64 d][64 k] bf16 with padded stride 72 -> 9.2 KB
    __shared__ ushort lds_b[D_DIM * BSTRIDE];

    const int tid = threadIdx.x;
    const int bid = blockIdx.x;
    // XCD-aware mapping: 8 row-tiles of one (b,h) land on the same XCD (bid%8)
    const int batch   = (bid & 7) * 4 + (bid >> 6);   // 0..31
    const int rowtile = (bid >> 3) & 7;               // 0..7
    const int row0    = rowtile * BM;

    const float* Abase = x1 + (size_t)batch * (S_DIM * S_DIM) + (size_t)row0 * S_DIM;
    const float* Bbase = x2 + (size_t)batch * (S_DIM * D_DIM);
    float*       Cbase = out + (size_t)batch * (S_DIM * D_DIM) + (size_t)row0 * D_DIM;

    const int w = tid >> 6;   // wave 0..7
    const int l = tid & 63;   // lane

    // ---- A staging: thread covers 16 floats of one row per chunk ----
    const int ar  = tid >> 2;        // row 0..127
    const int akq = tid & 3;         // 16-float quarter
    const float* aptr = Abase + (size_t)ar * S_DIM + akq * 16;
    const int aw_swz  = (ar & 7) << 3;                 // XOR in u16 units
    const int aw_base = ar * KC + akq * 16;
    const int aw0 = (aw_base    ) ^ aw_swz;
    const int aw1 = (aw_base + 8) ^ aw_swz;

    // ---- B staging: lane = d, wave picks k-groups ----
    const int bd  = l;
    const int bk0 = w * 4;           // k-local base (+32 for second half)

    // ---- fragment indices ----
    const int wm = w >> 1, wn = w & 1;      // wave grid 4m x 2n, tile 32x32
    const int fr = l & 15, fg = l >> 4;
    int aidx[2][2], bidx[2][2];
    #pragma unroll
    for (int mf = 0; mf < 2; ++mf) {
        const int row = wm * 32 + mf * 16 + fr;
        #pragma unroll
        for (int ks = 0; ks < 2; ++ks)
            aidx[mf][ks] = (row * KC + ks * 32 + fg * 8) ^ ((row & 7) << 3);
    }
    #pragma unroll
    for (int nf = 0; nf < 2; ++nf) {
        const int col = wn * 32 + nf * 16 + fr;
        #pragma unroll
        for (int ks = 0; ks < 2; ++ks)
            bidx[nf][ks] = col * BSTRIDE + ks * 32 + fg * 8;
    }

    float areg[16];
    float breg[8];

    auto load_chunk = [&](int t) {
        const float* p = aptr + t * KC;
        #pragma unroll
        for (int i = 0; i < 4; ++i) {
            float4 v = *reinterpret_cast<const float4*>(p + i * 4);
            areg[i * 4 + 0] = v.x; areg[i * 4 + 1] = v.y;
            areg[i * 4 + 2] = v.z; areg[i * 4 + 3] = v.w;
        }
        const float* bp = Bbase + (size_t)t * KC * D_DIM + bd;
        #pragma unroll
        for (int i = 0; i < 2; ++i)
            #pragma unroll
            for (int j = 0; j < 4; ++j)
                breg[i * 4 + j] = bp[(bk0 + 32 * i + j) * D_DIM];
    };

    auto store_lds = [&]() {
        short8_t v0, v1;
        #pragma unroll
        for (int j = 0; j < 8; ++j) v0[j] = (short)f2bf(areg[j]);
        #pragma unroll
        for (int j = 0; j < 8; ++j) v1[j] = (short)f2bf(areg[8 + j]);
        *reinterpret_cast<short8_t*>(&lds_a[aw0]) = v0;
        *reinterpret_cast<short8_t*>(&lds_a[aw1]) = v1;
        #pragma unroll
        for (int i = 0; i < 2; ++i) {
            short4_t bv;
            #pragma unroll
            for (int j = 0; j < 4; ++j) bv[j] = (short)f2bf(breg[i * 4 + j]);
            *reinterpret_cast<short4_t*>(&lds_b[bd * BSTRIDE + bk0 + 32 * i]) = bv;
        }
    };

    f32x4 acc[2][2];
    #pragma unroll
    for (int mf = 0; mf < 2; ++mf)
        #pragma unroll
        for (int nf = 0; nf < 2; ++nf)
            acc[mf][nf] = f32x4{0.f, 0.f, 0.f, 0.f};

    load_chunk(0);

    for (int t = 0; t < NCHUNK; ++t) {
        __syncthreads();               // LDS free (prev chunk consumed)
        store_lds();                   // regs -> LDS (bf16)
        __syncthreads();               // chunk visible
        if (t + 1 < NCHUNK) load_chunk(t + 1);   // prefetch overlaps MFMA

        short8_t af[2][2], bf[2][2];
        #pragma unroll
        for (int mf = 0; mf < 2; ++mf)
            #pragma unroll
            for (int ks = 0; ks < 2; ++ks)
                af[mf][ks] = *reinterpret_cast<const short8_t*>(&lds_a[aidx[mf][ks]]);
        #pragma unroll
        for (int nf = 0; nf < 2; ++nf)
            #pragma unroll
            for (int ks = 0; ks < 2; ++ks)
                bf[nf][ks] = *reinterpret_cast<const short8_t*>(&lds_b[bidx[nf][ks]]);

        #pragma unroll
        for (int ks = 0; ks < 2; ++ks)
            #pragma unroll
            for (int mf = 0; mf < 2; ++mf)
                #pragma unroll
                for (int nf = 0; nf < 2; ++nf)
                    acc[mf][nf] = __builtin_amdgcn_mfma_f32_16x16x32_bf16(
                        af[mf][ks], bf[nf][ks], acc[mf][nf], 0, 0, 0);
    }

    // epilogue: C/D layout col = lane&15, row = (lane>>4)*4 + j  [m89-verified]
    #pragma unroll
    for (int mf = 0; mf < 2; ++mf)
        #pragma unroll
        for (int nf = 0; nf < 2; ++nf)
            #pragma unroll
            for (int j = 0; j < 4; ++j) {
                const int r = wm * 32 + mf * 16 + fg * 4 + j;
                const int c = wn * 32 + nf * 16 + fr;
                Cbase[(size_t)r * D_DIM + c] = acc[mf][nf][j];
            }
}

extern "C" void kernel_launch(void* const* d_in, const int* in_sizes, int n_in,
                              void* d_out, int out_size, void* d_ws, size_t ws_size,
                              hipStream_t stream) {
    const float* x1 = (const float*)d_in[0];
    const float* x2 = (const float*)d_in[1];
    float* out = (float*)d_out;
    dim3 grid(256), block(THREADS);
    gemm_sm_kernel<<<grid, block, 0, stream>>>(x1, x2, out);
}

// Round 2
// 28.170 us; speedup vs baseline: 1.1498x; 1.1498x over previous
//
#include <hip/hip_runtime.h>
#include <hip/hip_bf16.h>

typedef __attribute__((ext_vector_type(8))) short short8_t;
typedef __attribute__((ext_vector_type(4))) short short4_t;
typedef __attribute__((ext_vector_type(4))) float f32x4;

#define S_DIM   1024
#define D_DIM   64
#define BM      128
#define KC      64
#define NCHUNK  (S_DIM / KC)   // 16
#define BSTRIDE 72             // u16 per row of BmT chunk (144B, 16B-aligned, bank-spread)
#define THREADS 512

__device__ __forceinline__ ushort f2bf(float f) {
    __hip_bfloat16 h = __float2bfloat16(f);   // RTNE
    return __builtin_bit_cast(ushort, h);
}

// Raw-barrier publish: waits only LDS ops (ds_write visibility), leaves global
// loads IN FLIGHT across the barrier (the __syncthreads vmcnt(0) drain was the
// R1 bottleneck). sched_barrier(0) pins memory ops on both sides.
#define SYNC() do { \
    __builtin_amdgcn_sched_barrier(0); \
    asm volatile("s_waitcnt lgkmcnt(0)"); \
    __builtin_amdgcn_s_barrier(); \
    __builtin_amdgcn_sched_barrier(0); \
} while (0)

__global__ __launch_bounds__(THREADS, 1)
void gemm_sm_kernel(const float* __restrict__ x1,
                    const float* __restrict__ x2,
                    float* __restrict__ out) {
    // double-buffered chunks: A [128][64] bf16 XOR-swizzled, B^T [64 d][64 k] pad-72
    __shared__ ushort lds_a[2][BM * KC];
    __shared__ ushort lds_b[2][D_DIM * BSTRIDE];

    const int tid = threadIdx.x;
    const int bid = blockIdx.x;
    // XCD-aware: 8 row-tiles of one (b,h) share an XCD's L2 (B chunk reuse)
    const int batch   = (bid & 7) * 4 + (bid >> 6);   // 0..31
    const int rowtile = (bid >> 3) & 7;               // 0..7
    const int row0    = rowtile * BM;

    const float* Abase = x1 + (size_t)batch * (S_DIM * S_DIM) + (size_t)row0 * S_DIM;
    const float* Bbase = x2 + (size_t)batch * (S_DIM * D_DIM);
    float*       Cbase = out + (size_t)batch * (S_DIM * D_DIM) + (size_t)row0 * D_DIM;

    const int w = tid >> 6;   // wave 0..7
    const int l = tid & 63;   // lane

    // ---- A staging: thread covers 16 floats of one row per chunk ----
    const int ar  = tid >> 2;        // row 0..127
    const int akq = tid & 3;         // 16-float quarter
    const float* aptr = Abase + (size_t)ar * S_DIM + akq * 16;
    const int aw_swz  = (ar & 7) << 3;                 // XOR in u16 units
    const int aw_base = ar * KC + akq * 16;
    const int aw0 = (aw_base    ) ^ aw_swz;
    const int aw1 = (aw_base + 8) ^ aw_swz;

    // ---- B staging: lane = d, wave picks k-groups ----
    const int bd  = l;
    const int bk0 = w * 4;           // k-local base (+32 for second half)

    // ---- fragment indices ----
    const int wm = w >> 1, wn = w & 1;      // wave grid 4m x 2n, tile 32x32
    const int fr = l & 15, fg = l >> 4;
    int aidx[2][2], bidx[2][2];
    #pragma unroll
    for (int mf = 0; mf < 2; ++mf) {
        const int row = wm * 32 + mf * 16 + fr;
        #pragma unroll
        for (int ks = 0; ks < 2; ++ks)
            aidx[mf][ks] = (row * KC + ks * 32 + fg * 8) ^ ((row & 7) << 3);
    }
    #pragma unroll
    for (int nf = 0; nf < 2; ++nf) {
        const int col = wn * 32 + nf * 16 + fr;
        #pragma unroll
        for (int ks = 0; ks < 2; ++ks)
            bidx[nf][ks] = col * BSTRIDE + ks * 32 + fg * 8;
    }

    // 2-deep register prefetch buffers (named -> static indexing, no scratch)
    float a0[16], a1[16], b0[8], b1[8];

    auto load_chunk = [&](int t, float (&A)[16], float (&B)[8]) {
        const float* p = aptr + t * KC;
        #pragma unroll
        for (int i = 0; i < 4; ++i) {
            float4 v = *reinterpret_cast<const float4*>(p + i * 4);
            A[i * 4 + 0] = v.x; A[i * 4 + 1] = v.y;
            A[i * 4 + 2] = v.z; A[i * 4 + 3] = v.w;
        }
        const float* bp = Bbase + (size_t)t * KC * D_DIM + bd;
        #pragma unroll
        for (int i = 0; i < 2; ++i)
            #pragma unroll
            for (int j = 0; j < 4; ++j)
                B[i * 4 + j] = bp[(bk0 + 32 * i + j) * D_DIM];
    };

    auto store_chunk = [&](ushort* la, ushort* lb,
                           const float (&A)[16], const float (&B)[8]) {
        short8_t v0, v1;
        #pragma unroll
        for (int j = 0; j < 8; ++j) v0[j] = (short)f2bf(A[j]);
        #pragma unroll
        for (int j = 0; j < 8; ++j) v1[j] = (short)f2bf(A[8 + j]);
        *reinterpret_cast<short8_t*>(&la[aw0]) = v0;
        *reinterpret_cast<short8_t*>(&la[aw1]) = v1;
        #pragma unroll
        for (int i = 0; i < 2; ++i) {
            short4_t bv;
            #pragma unroll
            for (int j = 0; j < 4; ++j) bv[j] = (short)f2bf(B[i * 4 + j]);
            *reinterpret_cast<short4_t*>(&lb[bd * BSTRIDE + bk0 + 32 * i]) = bv;
        }
    };

    f32x4 acc[2][2];
    #pragma unroll
    for (int mf = 0; mf < 2; ++mf)
        #pragma unroll
        for (int nf = 0; nf < 2; ++nf)
            acc[mf][nf] = f32x4{0.f, 0.f, 0.f, 0.f};

    auto compute = [&](const ushort* la, const ushort* lb) {
        short8_t af[2][2], bf[2][2];
        #pragma unroll
        for (int mf = 0; mf < 2; ++mf)
            #pragma unroll
            for (int ks = 0; ks < 2; ++ks)
                af[mf][ks] = *reinterpret_cast<const short8_t*>(&la[aidx[mf][ks]]);
        #pragma unroll
        for (int nf = 0; nf < 2; ++nf)
            #pragma unroll
            for (int ks = 0; ks < 2; ++ks)
                bf[nf][ks] = *reinterpret_cast<const short8_t*>(&lb[bidx[nf][ks]]);
        #pragma unroll
        for (int ks = 0; ks < 2; ++ks)
            #pragma unroll
            for (int mf = 0; mf < 2; ++mf)
                #pragma unroll
                for (int nf = 0; nf < 2; ++nf)
                    acc[mf][nf] = __builtin_amdgcn_mfma_f32_16x16x32_bf16(
                        af[mf][ks], bf[nf][ks], acc[mf][nf], 0, 0, 0);
    };

    // ---- pipeline: chunk t in regs (t&1 ? a1 : a0); LDS buf = t&1 ----
    load_chunk(0, a0, b0);
    load_chunk(1, a1, b1);
    store_chunk(&lds_a[0][0], &lds_b[0][0], a0, b0);   // counted vmcnt: chunk1 stays in flight
    SYNC();

    #pragma unroll 1
    for (int ti = 0; ti < NCHUNK; ti += 2) {
        // t = ti (even): compute buf0(chunk t); store chunk t+1 -> buf1; issue chunk t+2
        if (ti + 2 < NCHUNK) load_chunk(ti + 2, a0, b0);
        store_chunk(&lds_a[1][0], &lds_b[1][0], a1, b1);
        compute(&lds_a[0][0], &lds_b[0][0]);
        SYNC();

        // t = ti+1 (odd): compute buf1(chunk t+1); store chunk t+2 -> buf0; issue chunk t+3
        if (ti + 3 < NCHUNK) load_chunk(ti + 3, a1, b1);
        if (ti + 2 < NCHUNK) store_chunk(&lds_a[0][0], &lds_b[0][0], a0, b0);
        compute(&lds_a[1][0], &lds_b[1][0]);
        SYNC();
    }

    // epilogue: C/D layout col = lane&15, row = (lane>>4)*4 + j  [m89-verified]
    #pragma unroll
    for (int mf = 0; mf < 2; ++mf)
        #pragma unroll
        for (int nf = 0; nf < 2; ++nf)
            #pragma unroll
            for (int j = 0; j < 4; ++j) {
                const int r = wm * 32 + mf * 16 + fg * 4 + j;
                const int c = wn * 32 + nf * 16 + fr;
                Cbase[(size_t)r * D_DIM + c] = acc[mf][nf][j];
            }
}

extern "C" void kernel_launch(void* const* d_in, const int* in_sizes, int n_in,
                              void* d_out, int out_size, void* d_ws, size_t ws_size,
                              hipStream_t stream) {
    const float* x1 = (const float*)d_in[0];
    const float* x2 = (const float*)d_in[1];
    float* out = (float*)d_out;
    dim3 grid(256), block(THREADS);
    gemm_sm_kernel<<<grid, block, 0, stream>>>(x1, x2, out);
}